// Round 5
// baseline (2226.342 us; speedup 1.0000x reference)
//
#include <hip/hip_runtime.h>
#include <stdint.h>
#include <math.h>

#define T_ 4
#define B_ 16
#define C_ 256
#define N_ 1024
#define HD_ 1024
#define HEADS_ 8
#define DH_ 32

typedef float v2f  __attribute__((ext_vector_type(2)));
typedef float f4v  __attribute__((ext_vector_type(4)));

// v_pk_fma_f32 with op_sel broadcasting one 32-bit half of src0 to both halves.
// Two independent IEEE fp32 FMAs; bit-exact per-output chains.
#define PKL(a, w, x) asm volatile("v_pk_fma_f32 %0, %1, %2, %0 op_sel:[0,0,0] op_sel_hi:[0,1,1]" : "+v"(a) : "v"(w), "v"(x))
#define PKH(a, w, x) asm volatile("v_pk_fma_f32 %0, %1, %2, %0 op_sel:[1,0,0] op_sel_hi:[1,1,1]" : "+v"(a) : "v"(w), "v"(x))

template<int N> __device__ __forceinline__ void waitv(){
  asm volatile("s_waitcnt vmcnt(%0)" :: "i"(N) : "memory");
}
__device__ __forceinline__ void sb(){ __builtin_amdgcn_sched_barrier(0); }

// Wt[k][ooff+o] = W[o][k].  W: [O][K] row-major.  grid (K/32, O/32), 256 thr.
__global__ __launch_bounds__(256)
void transW(const float* __restrict__ W, float* __restrict__ Wt,
            int O, int K, int ostride, int ooff)
{
  __shared__ float tl[32][33];
  int k0 = blockIdx.x*32, o0 = blockIdx.y*32;
  int tid = threadIdx.x;
  int a = tid & 31, bq = tid >> 5;
#pragma unroll
  for (int i=0;i<4;i++)
    tl[bq+8*i][a] = W[(size_t)(o0+bq+8*i)*K + k0 + a];
  __syncthreads();
#pragma unroll
  for (int i=0;i<4;i++)
    Wt[(size_t)(k0+bq+8*i)*ostride + ooff + o0 + a] = tl[a][bq+8*i];
}

__global__ __launch_bounds__(256)
void packBn3(const float* __restrict__ a, const float* __restrict__ b,
             const float* __restrict__ c, float* __restrict__ o)
{
  int i = blockIdx.x*256 + threadIdx.x;            // 0..1023 = [4][256]
  int r = i >> 8, ci = i & 255;
  o[(size_t)r*768 + ci]       = a[i];
  o[(size_t)r*768 + 256 + ci] = b[i];
  o[(size_t)r*768 + 512 + ci] = c[i];
}

template<typename T> struct XRT;
template<> struct XRT<float>  { using t = f4v; };
template<> struct XRT<uint8_t>{ using t = uint32_t; };

// Y = Wt^T @ X (+bias) -> BN -> LIF, t-loop inside (LIF state in regs).
// Pure-VMEM streaming GEMM (Round-2-verified structure): no LDS, no barriers.
// Per wave: UO wave-uniform o-rows (W via saddr broadcast dwordx4 -> VGPR),
// per lane 4 consecutive n.  Ring of EIGHT k-slots, prefetch distance 6
// (vs verified round-2's 4/2); all waits counted vmcnt (in-order retire);
// sched_barrier(0) after each wait fences register-only consumers.
// launch_bounds relaxed per-UO so the ring never spills (spill ops would
// corrupt the hand-counted vmcnt).
// Numeric contract: per output, strictly k-ascending fp32 FMA chain
// (identical bit-path to all prior passing kernels; absmax 0.0).
template<int KDIM,int ODIM,int UO,bool HAS_BIAS,int MODE,typename TIn>
__global__ __launch_bounds__(256, (UO==8)?2:3)
void rgemm(const TIn* __restrict__ X, const float* __restrict__ Wt,
           const float* __restrict__ bias, const float* __restrict__ bn,
           const float* __restrict__ resid, void* __restrict__ out, float vth)
{
  constexpr int ESZ = (int)sizeof(TIn);
  constexpr int P   = UO/4 + 1;            // VMEM ops issued per k
  const int tid  = threadIdx.x;
  const int lane = tid & 63;
  const int wid  = __builtin_amdgcn_readfirstlane(tid >> 6);
  const int b    = blockIdx.z, n0 = blockIdx.x*256;
  const int ow   = blockIdx.y*(4*UO) + wid*UO;      // wave-uniform o-base

  f4v wr[8][UO/4];
  typename XRT<TIn>::t xr[8];
  v2f acc[UO][2], vli[UO][2];
#pragma unroll
  for (int i=0;i<UO;i++){ vli[i][0]=(v2f){0.f,0.f}; vli[i][1]=(v2f){0.f,0.f}; }

  uint32_t zv   = 0;                 // zero voffset (VGPR) for broadcast W loads
  uint32_t xoff = (uint32_t)(lane*4*ESZ);

#define ISSUE(sn) do{                                                          \
    if constexpr (UO==8)                                                       \
      asm volatile("global_load_dwordx4 %0, %2, %3\n\t"                        \
                   "global_load_dwordx4 %1, %2, %3 offset:16"                  \
                   : "=v"(wr[sn][0]), "=v"(wr[sn][1]) : "v"(zv), "s"(wb));     \
    else                                                                       \
      asm volatile("global_load_dwordx4 %0, %1, %2"                            \
                   : "=v"(wr[sn][0]) : "v"(zv), "s"(wb));                      \
    if constexpr (ESZ==4)                                                      \
      asm volatile("global_load_dwordx4 %0, %1, %2"                            \
                   : "=v"(xr[sn]) : "v"(xoff), "s"(xb));                       \
    else                                                                       \
      asm volatile("global_load_dword %0, %1, %2"                              \
                   : "=v"(xr[sn]) : "v"(xoff), "s"(xb));                       \
    wb += (uint64_t)ODIM*4; xb += (uint64_t)N_*ESZ; }while(0)

#define COMPUTE(s) do{ v2f xa, xb2;                                            \
    if constexpr (ESZ==4){                                                     \
      xa  = __builtin_shufflevector(xr[s],xr[s],0,1);                          \
      xb2 = __builtin_shufflevector(xr[s],xr[s],2,3);                          \
    } else {                                                                   \
      uint32_t u = xr[s];                                                      \
      xa  = (v2f){ (float)(u & 255u), (float)((u>>8) & 255u) };                \
      xb2 = (v2f){ (float)((u>>16) & 255u), (float)(u>>24) };                  \
    }                                                                          \
    _Pragma("unroll")                                                          \
    for (int j=0;j<UO/4;j++){                                                  \
      v2f wa = __builtin_shufflevector(wr[s][j],wr[s][j],0,1);                 \
      v2f wc = __builtin_shufflevector(wr[s][j],wr[s][j],2,3);                 \
      PKL(acc[4*j+0][0],wa,xa); PKL(acc[4*j+0][1],wa,xb2);                     \
      PKH(acc[4*j+1][0],wa,xa); PKH(acc[4*j+1][1],wa,xb2);                     \
      PKL(acc[4*j+2][0],wc,xa); PKL(acc[4*j+2][1],wc,xb2);                     \
      PKH(acc[4*j+3][0],wc,xa); PKH(acc[4*j+3][1],wc,xb2);                     \
    } }while(0)

// issue-first (round-2 pattern): post-issue outstanding = 7P, wait<6P>
// retires exactly the consumed slot (in-order vmcnt retire).
#define STEP(s, sn)  do{ ISSUE(sn); waitv<6*P>(); sb(); COMPUTE(s); }while(0)
#define STEPN(s, m)  do{ waitv<(m)*P>(); sb(); COMPUTE(s); }while(0)

  const uint64_t wb0 = (uint64_t)(uintptr_t)(Wt + ow);

  for (int t=0;t<T_;t++){
    asm volatile("s_waitcnt vmcnt(0)" ::: "memory");   // counter state := 0
    sb();
    uint64_t wb = wb0;
    uint64_t xb = (uint64_t)(uintptr_t)X
                + ((size_t)(t*B_+b)*KDIM)*(size_t)N_*ESZ + (size_t)n0*ESZ;
    ISSUE(0); ISSUE(1); ISSUE(2); ISSUE(3); ISSUE(4); ISSUE(5);
#pragma unroll
    for (int i=0;i<UO;i++){ acc[i][0]=(v2f){0.f,0.f}; acc[i][1]=(v2f){0.f,0.f}; }

#pragma unroll 1
    for (int g=0; g<(KDIM-8)/8; ++g){
      STEP(0,6); STEP(1,7); STEP(2,0); STEP(3,1);
      STEP(4,2); STEP(5,3); STEP(6,4); STEP(7,5);
    }
    // tail: last 8 k-steps; only first two still have a k+6 to issue
    STEP(0,6); STEP(1,7);
    STEPN(2,5); STEPN(3,4); STEPN(4,3); STEPN(5,2); STEPN(6,1); STEPN(7,0);

    // epilogue: bias -> BN -> LIF -> store (identical formula chain)
#pragma unroll
    for (int i=0;i<UO;i++){
      const int o = ow + i;
      const float g  = bn[o];
      const float be = bn[ODIM + o];
      const float m  = bn[2*ODIM + o];
      const float rs = 1.0f / sqrtf(bn[3*ODIM + o] + 1e-5f);
      const float bi = HAS_BIAS ? bias[o] : 0.0f;
      float sv[4];
#pragma unroll
      for (int jj=0;jj<4;jj++){
        float y  = acc[i][jj>>1][jj&1] + bi;
        float yb = (g*(y - m))*rs + be;
        float vv = vli[i][jj>>1][jj&1];
        vv += (yb - vv)*0.5f;
        float s = (vv >= vth) ? 1.0f : 0.0f;
        vli[i][jj>>1][jj&1] = (s!=0.0f) ? 0.0f : vv;
        sv[jj] = s;
      }
      const size_t base = ((size_t)(t*B_+b)*ODIM + o)*N_ + n0 + 4*lane;
      if (MODE==0){
        uchar4 pa;
        pa.x=(uint8_t)sv[0]; pa.y=(uint8_t)sv[1]; pa.z=(uint8_t)sv[2]; pa.w=(uint8_t)sv[3];
        *(uchar4*)((uint8_t*)out + base) = pa;
      } else {
        const float4 r0 = *(const float4*)&resid[base];
        *(float4*)&((float*)out)[base] =
          make_float4(r0.x+sv[0], r0.y+sv[1], r0.z+sv[2], r0.w+sv[3]);
      }
    }
  }
#undef ISSUE
#undef COMPUTE
#undef STEP
#undef STEPN
}

// kv[t,b,h,d,e] = sum_n k[d,n]*v[e,n] over binary byte spikes (exact popc).
__global__ __launch_bounds__(256)
void kv_kernel(const uint8_t* __restrict__ qkv, float* __restrict__ kvout)
{
  int blk = blockIdx.x;          // (t*B+b)*HEADS + h
  int h = blk & 7, tb = blk >> 3;
  int tid = threadIdx.x;
  int e = tid & 31, d0 = (tid >> 5) * 4;
  const uint8_t* kp = qkv + ((size_t)tb*768 + 256 + h*DH_)*N_;
  const uint8_t* vp = qkv + ((size_t)tb*768 + 512 + h*DH_)*N_;
  const uint4* vr = (const uint4*)(vp + (size_t)e*N_);
  const uint4* k0 = (const uint4*)(kp + (size_t)(d0+0)*N_);
  const uint4* k1 = (const uint4*)(kp + (size_t)(d0+1)*N_);
  const uint4* k2 = (const uint4*)(kp + (size_t)(d0+2)*N_);
  const uint4* k3 = (const uint4*)(kp + (size_t)(d0+3)*N_);
  int s0=0,s1=0,s2=0,s3=0;
  for (int q=0;q<N_/16;q++){
    uint4 vv = vr[q];
    uint4 a0 = k0[q], a1 = k1[q], a2 = k2[q], a3 = k3[q];
    s0 += __popc(a0.x&vv.x)+__popc(a0.y&vv.y)+__popc(a0.z&vv.z)+__popc(a0.w&vv.w);
    s1 += __popc(a1.x&vv.x)+__popc(a1.y&vv.y)+__popc(a1.z&vv.z)+__popc(a1.w&vv.w);
    s2 += __popc(a2.x&vv.x)+__popc(a2.y&vv.y)+__popc(a2.z&vv.z)+__popc(a2.w&vv.w);
    s3 += __popc(a3.x&vv.x)+__popc(a3.y&vv.y)+__popc(a3.z&vv.z)+__popc(a3.w&vv.w);
  }
  float* kvp = kvout + (size_t)blk*DH_*DH_;
  kvp[(d0+0)*DH_ + e] = (float)s0;
  kvp[(d0+1)*DH_ + e] = (float)s1;
  kvp[(d0+2)*DH_ + e] = (float)s2;
  kvp[(d0+3)*DH_ + e] = (float)s3;
}

// a[e,n] = 0.125 * sum_d q[d,n]*kv[d,e]; LIF vth=0.5 (exact dyadic).
__global__ __launch_bounds__(256)
void attn_lif_kernel(const uint8_t* __restrict__ qkv, const float* __restrict__ kv,
                     uint8_t* __restrict__ as_)
{
  int tid = threadIdx.x;
  int n = blockIdx.x*256 + tid;
  int h = blockIdx.y, b = blockIdx.z;
  __shared__ float kvL[DH_*DH_];
  float v[DH_];
#pragma unroll
  for (int e=0;e<DH_;e++) v[e]=0.0f;
  for (int t=0;t<T_;t++){
    const float* kvp = kv + ((size_t)((t*B_+b)*HEADS_+h))*DH_*DH_;
    __syncthreads();
#pragma unroll
    for (int r=0;r<4;r++) kvL[tid+256*r] = kvp[tid+256*r];
    __syncthreads();
    const uint8_t* qp = qkv + ((size_t)(t*B_+b)*768 + h*DH_)*N_ + n;
    float qv[DH_];
#pragma unroll
    for (int d=0;d<DH_;d++) qv[d] = (float)qp[(size_t)d*N_];
    uint8_t* op = as_ + ((size_t)(t*B_+b)*C_ + h*DH_)*N_ + n;
#pragma unroll
    for (int e=0;e<DH_;e++){
      float a=0.0f;
#pragma unroll
      for (int d=0;d<DH_;d++) a += qv[d]*kvL[d*DH_+e];
      a *= 0.125f;
      float vv = v[e];
      vv += (a - vv)*0.5f;
      float s = (vv >= 0.5f) ? 1.0f : 0.0f;
      v[e] = (s!=0.0f) ? 0.0f : vv;
      op[(size_t)e*N_] = (uint8_t)s;
    }
  }
}

extern "C" void kernel_launch(void* const* d_in, const int* in_sizes, int n_in,
                              void* d_out, int out_size, void* d_ws, size_t ws_size,
                              hipStream_t stream)
{
  const float* x      = (const float*)d_in[0];
  const float* wq     = (const float*)d_in[2];
  const float* bn_q   = (const float*)d_in[3];
  const float* wk     = (const float*)d_in[4];
  const float* bn_k   = (const float*)d_in[5];
  const float* wv     = (const float*)d_in[6];
  const float* bn_v   = (const float*)d_in[7];
  const float* wproj  = (const float*)d_in[8];
  const float* bproj  = (const float*)d_in[9];
  const float* bnproj = (const float*)d_in[10];
  const float* wfc1   = (const float*)d_in[11];
  const float* bfc1   = (const float*)d_in[12];
  const float* bnfc1  = (const float*)d_in[13];
  const float* wfc2   = (const float*)d_in[14];
  const float* bfc2   = (const float*)d_in[15];
  const float* bnfc2  = (const float*)d_in[16];

  char* ws = (char*)d_ws;
  const size_t TB = (size_t)T_*B_;
  uint8_t* qkv = (uint8_t*)ws;                       // TB*768*N
  uint8_t* as_ = (uint8_t*)ws + TB*768*N_;           // TB*256*N
  uint8_t* h1s = (uint8_t*)ws;                       // TB*1024*N (overlay)
  size_t off = TB*768*N_ + TB*(size_t)C_*N_;
  float* xnew = (float*)(ws + off); off += TB*(size_t)C_*N_*4;
  float* WtQ  = (float*)(ws + off); off += (size_t)C_*768*4;
  float* WtP  = (float*)(ws + off); off += (size_t)C_*C_*4;
  float* WtF1 = (float*)(ws + off); off += (size_t)C_*HD_*4;
  float* WtF2 = (float*)(ws + off); off += (size_t)HD_*C_*4;
  float* bnQ  = (float*)(ws + off); off += 4*768*4;
  float* kvb  = (float*)(ws + off); off += TB*HEADS_*DH_*DH_*4;

  dim3 blk(256);
  transW<<<dim3(8,8),blk,0,stream>>>(wq, WtQ, 256, 256, 768, 0);
  transW<<<dim3(8,8),blk,0,stream>>>(wk, WtQ, 256, 256, 768, 256);
  transW<<<dim3(8,8),blk,0,stream>>>(wv, WtQ, 256, 256, 768, 512);
  transW<<<dim3(8,8),blk,0,stream>>>(wproj, WtP, 256, 256, 256, 0);
  transW<<<dim3(8,32),blk,0,stream>>>(wfc1, WtF1, 1024, 256, 1024, 0);
  transW<<<dim3(32,8),blk,0,stream>>>(wfc2, WtF2, 256, 1024, 256, 0);
  packBn3<<<dim3(4),blk,0,stream>>>(bn_q, bn_k, bn_v, bnQ);

  // fused QKV GEMM -> spikes
  rgemm<C_,768,8,false,0,float><<<dim3(4,24,16),blk,0,stream>>>(
      x, WtQ, nullptr, bnQ, nullptr, qkv, 1.0f);
  kv_kernel<<<dim3(T_*B_*HEADS_),blk,0,stream>>>(qkv, kvb);
  attn_lif_kernel<<<dim3(4,HEADS_,B_),blk,0,stream>>>(qkv, kvb, as_);
  // proj -> xnew = x + attn spike
  rgemm<C_,C_,4,true,1,uint8_t><<<dim3(4,16,16),blk,0,stream>>>(
      as_, WtP, bproj, bnproj, x, xnew, 1.0f);
  // fc1 -> h1 spikes (overlays dead qkv/as_)
  rgemm<C_,HD_,8,true,0,float><<<dim3(4,32,16),blk,0,stream>>>(
      xnew, WtF1, bfc1, bnfc1, nullptr, h1s, 1.0f);
  // fc2 -> out = xnew + mlp spike
  rgemm<HD_,C_,4,true,1,uint8_t><<<dim3(4,16,16),blk,0,stream>>>(
      h1s, WtF2, bfc2, bnfc2, xnew, d_out, 1.0f);
}

// Round 6
// 1462.486 us; speedup vs baseline: 1.5223x; 1.5223x over previous
//
#include <hip/hip_runtime.h>
#include <stdint.h>
#include <math.h>

#define T_ 4
#define B_ 16
#define C_ 256
#define N_ 1024
#define HD_ 1024
#define HEADS_ 8
#define DH_ 32

typedef float v2f  __attribute__((ext_vector_type(2)));
typedef float f4v  __attribute__((ext_vector_type(4)));
typedef float f16v __attribute__((ext_vector_type(16)));

// v_pk_fma_f32, src0 = SGPR pair, op_sel broadcasts one 32-bit half of src0 to
// both lanes of the packed op. Two independent IEEE fp32 FMAs; bit-exact
// per-output chains. (Verified numerically correct in round 1: absmax 0.0.)
#define PKLs(a, w, x) asm volatile("v_pk_fma_f32 %0, %1, %2, %0 op_sel:[0,0,0] op_sel_hi:[0,1,1]" : "+v"(a) : "s"(w), "v"(x))
#define PKHs(a, w, x) asm volatile("v_pk_fma_f32 %0, %1, %2, %0 op_sel:[1,0,0] op_sel_hi:[1,1,1]" : "+v"(a) : "s"(w), "v"(x))

// Full lgkm drain + scheduler fence (rule #18). Full drain => SMEM
// out-of-order retirement cannot bite; issued a compute-half earlier => ~free.
__device__ __forceinline__ void drainl(){
  asm volatile("s_waitcnt lgkmcnt(0)" ::: "memory");
  __builtin_amdgcn_sched_barrier(0);
}

// Wp[((k>>1)*(OD/8) + (o+ooff)/8)*16 + (k&1)*8 + (o+ooff)%8] = W[o][k]
// => one s_load_dwordx16 fetches a contiguous {2 k's} x {8 o's} W half-tile.
__global__ __launch_bounds__(256)
void packW(const float* __restrict__ W, float* __restrict__ Wp,
           int K, int OD, int ooff)
{
  int k = blockIdx.x*256 + threadIdx.x;
  int oo = blockIdx.y + ooff;
  Wp[((size_t)(k>>1)*(OD>>3) + (oo>>3))*16 + ((k&1)<<3) + (oo&7)]
      = W[(size_t)blockIdx.y*K + k];
}

__global__ __launch_bounds__(256)
void packBn3(const float* __restrict__ a, const float* __restrict__ b,
             const float* __restrict__ c, float* __restrict__ o)
{
  int i = blockIdx.x*256 + threadIdx.x;            // 0..1023 = [4][256]
  int r = i >> 8, ci = i & 255;
  o[(size_t)r*768 + ci]       = a[i];
  o[(size_t)r*768 + 256 + ci] = b[i];
  o[(size_t)r*768 + 512 + ci] = c[i];
}

template<typename T> struct VecT;
template<> struct VecT<float>  { using t = float4; };
template<> struct VecT<uint8_t>{ using t = uchar4; };
__device__ __forceinline__ float4 cvt4(float4 v){ return v; }
__device__ __forceinline__ float4 cvt4(uchar4 u){
  return make_float4((float)u.x,(float)u.y,(float)u.z,(float)u.w);
}

// ---------------------------------------------------------------------------
// Y = W @ X (+bias) -> BN -> LIF, t-loop inside block (LIF state in regs).
// Block: 256 thr, o-tile 32 (wave w owns o0+8w..+7, wave-uniform), n-tile 256
// (lane owns 4 consecutive n).  W: SGPRs via s_load_dwordx16 per 2-k half,
// double-buffered (zero VALU/LDS/L1 cost at use).  X: staged global->reg->LDS
// per 16-k chunk (round-0-verified barrier pattern), read 1 conflict-free
// ds_read_b128 per lane per k, double-buffered regs per half.
// All lgkm waits are FULL drains placed one compute-half after issue.
// Numeric contract: per output, strictly k-ascending fp32 FMA chain;
// epilogue formula chain identical to all verified rounds (absmax 0.0).
// ---------------------------------------------------------------------------
template<int KDIM,int ODIM,bool HAS_BIAS,int MODE,typename TIn>
__global__ __launch_bounds__(256,3)
void sgemm(const TIn* __restrict__ X, const float* __restrict__ Wp,
           const float* __restrict__ bias, const float* __restrict__ bn,
           const float* __restrict__ resid, void* __restrict__ out, float vth)
{
  using XV = typename VecT<TIn>::t;
  constexpr int NC = KDIM/16;                 // 16-k chunks per t
  __shared__ __align__(16) float Xs[2][16*256];

  const int tid  = threadIdx.x;
  const int lane = tid & 63;
  const int wid  = __builtin_amdgcn_readfirstlane(tid >> 6);
  const int b    = blockIdx.z, n0 = blockIdx.x*256, o0 = blockIdx.y*32;
  const int og   = (o0 >> 3) + wid;           // W o-group index, uniform
  const uint32_t laB =
      (uint32_t)(uintptr_t)(__attribute__((address_space(3))) float*)&Xs[0][0]
      + (uint32_t)(lane*16);

  v2f acc[8][2], vli[8][2];
#pragma unroll
  for (int i=0;i<8;i++){ vli[i][0]=(v2f){0.f,0.f}; vli[i][1]=(v2f){0.f,0.f}; }

  union WU { f16v v; v2f p[8]; };
  WU wbuf[2];
  f4v xbuf[2][2];
  XV  sreg[4];

  // stage-register load for global chunk ch = t*NC + c (plain C++, vmcnt,
  // compiler-managed; independent of the lgkm pipeline)
  auto ldstage = [&](int ch){
    const int t = ch / NC, c = ch % NC;
    const TIn* Xg = X + ((size_t)(t*B_+b)*KDIM + c*16)*N_ + n0 + (tid&63)*4;
#pragma unroll
    for (int r=0;r<4;r++)
      sreg[r] = *(const XV*)(Xg + (size_t)((tid>>6) + 4*r)*N_);
  };

  // issue W s_load + X ds_reads for half h (k = 2h,2h+1) of chunk c, buffer pb
#define ISSUEH(pb, c, h) do{                                                   \
    const float* wp_ = Wp + ((size_t)((c)*8 + (h))*(ODIM>>3) + og)*16;         \
    asm volatile("s_load_dwordx16 %0, %1, 0x0"                                 \
                 : "=s"(wbuf[(h)&1].v) : "s"(wp_));                            \
    uint32_t la_ = laB + (uint32_t)((pb)*16384 + (h)*2048);                    \
    asm volatile("ds_read_b128 %0, %2\n\tds_read_b128 %1, %2 offset:1024"      \
                 : "=v"(xbuf[(h)&1][0]), "=v"(xbuf[(h)&1][1]) : "v"(la_));     \
  }while(0)

  // compute half h: k=2h (e=0) then k=2h+1 (e=1); strict ascending-k order
#define CH(h) do{                                                              \
    _Pragma("unroll")                                                          \
    for (int e=0;e<2;e++){                                                     \
      v2f xa = __builtin_shufflevector(xbuf[(h)&1][e], xbuf[(h)&1][e], 0,1);   \
      v2f xc = __builtin_shufflevector(xbuf[(h)&1][e], xbuf[(h)&1][e], 2,3);   \
      _Pragma("unroll")                                                        \
      for (int j=0;j<4;j++){                                                   \
        PKLs(acc[2*j  ][0], wbuf[(h)&1].p[4*e+j], xa);                         \
        PKLs(acc[2*j  ][1], wbuf[(h)&1].p[4*e+j], xc);                         \
        PKHs(acc[2*j+1][0], wbuf[(h)&1].p[4*e+j], xa);                         \
        PKHs(acc[2*j+1][1], wbuf[(h)&1].p[4*e+j], xc);                         \
      }                                                                        \
    } }while(0)

  // one 16-k chunk: barriered LDS fill (verified round-0 pattern), then
  // 8 halves: drain -> issue(h+1) -> compute(h)
#define CHUNK(pb, t, c) do{                                                    \
    __syncthreads();                                                           \
    _Pragma("unroll")                                                          \
    for (int r=0;r<4;r++)                                                      \
      *(float4*)&Xs[pb][((tid>>6) + 4*r)*256 + (tid&63)*4] = cvt4(sreg[r]);    \
    __syncthreads();                                                           \
    { int nch = (t)*NC + (c) + 1; if (nch < T_*NC) ldstage(nch); }             \
    ISSUEH(pb,c,0);                                                            \
    drainl(); ISSUEH(pb,c,1); CH(0);                                           \
    drainl(); ISSUEH(pb,c,2); CH(1);                                           \
    drainl(); ISSUEH(pb,c,3); CH(2);                                           \
    drainl(); ISSUEH(pb,c,4); CH(3);                                           \
    drainl(); ISSUEH(pb,c,5); CH(4);                                           \
    drainl(); ISSUEH(pb,c,6); CH(5);                                           \
    drainl(); ISSUEH(pb,c,7); CH(6);                                           \
    drainl(); CH(7);                                                           \
  }while(0)

  ldstage(0);

  for (int t=0;t<T_;t++){
#pragma unroll
    for (int i=0;i<8;i++){ acc[i][0]=(v2f){0.f,0.f}; acc[i][1]=(v2f){0.f,0.f}; }

#pragma unroll 1
    for (int cc=0; cc<NC; cc+=2){
      CHUNK(0, t, cc);
      CHUNK(1, t, cc+1);
    }

    // epilogue: bias -> BN -> LIF -> store (identical verified formula chain)
#pragma unroll
    for (int i=0;i<8;i++){
      const int o = o0 + wid*8 + i;
      const float g  = bn[o];
      const float be = bn[ODIM + o];
      const float m  = bn[2*ODIM + o];
      const float rs = 1.0f / sqrtf(bn[3*ODIM + o] + 1e-5f);
      const float bi = HAS_BIAS ? bias[o] : 0.0f;
      float sv[4];
#pragma unroll
      for (int jj=0;jj<4;jj++){
        float y  = acc[i][jj>>1][jj&1] + bi;
        float yb = (g*(y - m))*rs + be;
        float vv = vli[i][jj>>1][jj&1];
        vv += (yb - vv)*0.5f;
        float s = (vv >= vth) ? 1.0f : 0.0f;
        vli[i][jj>>1][jj&1] = (s!=0.0f) ? 0.0f : vv;
        sv[jj] = s;
      }
      const size_t base = ((size_t)(t*B_+b)*ODIM + o)*N_ + n0 + 4*lane;
      if (MODE==0){
        uchar4 pa;
        pa.x=(uint8_t)sv[0]; pa.y=(uint8_t)sv[1]; pa.z=(uint8_t)sv[2]; pa.w=(uint8_t)sv[3];
        *(uchar4*)((uint8_t*)out + base) = pa;
      } else {
        const float4 r0 = *(const float4*)&resid[base];
        *(float4*)&((float*)out)[base] =
          make_float4(r0.x+sv[0], r0.y+sv[1], r0.z+sv[2], r0.w+sv[3]);
      }
    }
  }
#undef ISSUEH
#undef CH
#undef CHUNK
}

// kv[t,b,h,d,e] = sum_n k[d,n]*v[e,n] over binary byte spikes (exact popc).
__global__ __launch_bounds__(256)
void kv_kernel(const uint8_t* __restrict__ qkv, float* __restrict__ kvout)
{
  int blk = blockIdx.x;          // (t*B+b)*HEADS + h
  int h = blk & 7, tb = blk >> 3;
  int tid = threadIdx.x;
  int e = tid & 31, d0 = (tid >> 5) * 4;
  const uint8_t* kp = qkv + ((size_t)tb*768 + 256 + h*DH_)*N_;
  const uint8_t* vp = qkv + ((size_t)tb*768 + 512 + h*DH_)*N_;
  const uint4* vr = (const uint4*)(vp + (size_t)e*N_);
  const uint4* k0 = (const uint4*)(kp + (size_t)(d0+0)*N_);
  const uint4* k1 = (const uint4*)(kp + (size_t)(d0+1)*N_);
  const uint4* k2 = (const uint4*)(kp + (size_t)(d0+2)*N_);
  const uint4* k3 = (const uint4*)(kp + (size_t)(d0+3)*N_);
  int s0=0,s1=0,s2=0,s3=0;
  for (int q=0;q<N_/16;q++){
    uint4 vv = vr[q];
    uint4 a0 = k0[q], a1 = k1[q], a2 = k2[q], a3 = k3[q];
    s0 += __popc(a0.x&vv.x)+__popc(a0.y&vv.y)+__popc(a0.z&vv.z)+__popc(a0.w&vv.w);
    s1 += __popc(a1.x&vv.x)+__popc(a1.y&vv.y)+__popc(a1.z&vv.z)+__popc(a1.w&vv.w);
    s2 += __popc(a2.x&vv.x)+__popc(a2.y&vv.y)+__popc(a2.z&vv.z)+__popc(a2.w&vv.w);
    s3 += __popc(a3.x&vv.x)+__popc(a3.y&vv.y)+__popc(a3.z&vv.z)+__popc(a3.w&vv.w);
  }
  float* kvp = kvout + (size_t)blk*DH_*DH_;
  kvp[(d0+0)*DH_ + e] = (float)s0;
  kvp[(d0+1)*DH_ + e] = (float)s1;
  kvp[(d0+2)*DH_ + e] = (float)s2;
  kvp[(d0+3)*DH_ + e] = (float)s3;
}

// a[e,n] = 0.125 * sum_d q[d,n]*kv[d,e]; LIF vth=0.5 (exact dyadic).
__global__ __launch_bounds__(256)
void attn_lif_kernel(const uint8_t* __restrict__ qkv, const float* __restrict__ kv,
                     uint8_t* __restrict__ as_)
{
  int tid = threadIdx.x;
  int n = blockIdx.x*256 + tid;
  int h = blockIdx.y, b = blockIdx.z;
  __shared__ float kvL[DH_*DH_];
  float v[DH_];
#pragma unroll
  for (int e=0;e<DH_;e++) v[e]=0.0f;
  for (int t=0;t<T_;t++){
    const float* kvp = kv + ((size_t)((t*B_+b)*HEADS_+h))*DH_*DH_;
    __syncthreads();
#pragma unroll
    for (int r=0;r<4;r++) kvL[tid+256*r] = kvp[tid+256*r];
    __syncthreads();
    const uint8_t* qp = qkv + ((size_t)(t*B_+b)*768 + h*DH_)*N_ + n;
    float qv[DH_];
#pragma unroll
    for (int d=0;d<DH_;d++) qv[d] = (float)qp[(size_t)d*N_];
    uint8_t* op = as_ + ((size_t)(t*B_+b)*C_ + h*DH_)*N_ + n;
#pragma unroll
    for (int e=0;e<DH_;e++){
      float a=0.0f;
#pragma unroll
      for (int d=0;d<DH_;d++) a += qv[d]*kvL[d*DH_+e];
      a *= 0.125f;
      float vv = v[e];
      vv += (a - vv)*0.5f;
      float s = (vv >= 0.5f) ? 1.0f : 0.0f;
      v[e] = (s!=0.0f) ? 0.0f : vv;
      op[(size_t)e*N_] = (uint8_t)s;
    }
  }
}

extern "C" void kernel_launch(void* const* d_in, const int* in_sizes, int n_in,
                              void* d_out, int out_size, void* d_ws, size_t ws_size,
                              hipStream_t stream)
{
  const float* x      = (const float*)d_in[0];
  const float* wq     = (const float*)d_in[2];
  const float* bn_q   = (const float*)d_in[3];
  const float* wk     = (const float*)d_in[4];
  const float* bn_k   = (const float*)d_in[5];
  const float* wv     = (const float*)d_in[6];
  const float* bn_v   = (const float*)d_in[7];
  const float* wproj  = (const float*)d_in[8];
  const float* bproj  = (const float*)d_in[9];
  const float* bnproj = (const float*)d_in[10];
  const float* wfc1   = (const float*)d_in[11];
  const float* bfc1   = (const float*)d_in[12];
  const float* bnfc1  = (const float*)d_in[13];
  const float* wfc2   = (const float*)d_in[14];
  const float* bfc2   = (const float*)d_in[15];
  const float* bnfc2  = (const float*)d_in[16];

  char* ws = (char*)d_ws;
  const size_t TB = (size_t)T_*B_;
  uint8_t* qkv = (uint8_t*)ws;                       // TB*768*N
  uint8_t* as_ = (uint8_t*)ws + TB*768*N_;           // TB*256*N
  uint8_t* h1s = (uint8_t*)ws;                       // TB*1024*N (overlay)
  size_t off = TB*768*N_ + TB*(size_t)C_*N_;
  float* xnew = (float*)(ws + off); off += TB*(size_t)C_*N_*4;
  float* WpQ  = (float*)(ws + off); off += (size_t)C_*768*4;
  float* WpP  = (float*)(ws + off); off += (size_t)C_*C_*4;
  float* WpF1 = (float*)(ws + off); off += (size_t)C_*HD_*4;
  float* WpF2 = (float*)(ws + off); off += (size_t)HD_*C_*4;
  float* bnQ  = (float*)(ws + off); off += 4*768*4;
  float* kvb  = (float*)(ws + off); off += TB*HEADS_*DH_*DH_*4;

  dim3 blk(256);
  packW<<<dim3(1,256),blk,0,stream>>>(wq,    WpQ,  256,  768,   0);
  packW<<<dim3(1,256),blk,0,stream>>>(wk,    WpQ,  256,  768, 256);
  packW<<<dim3(1,256),blk,0,stream>>>(wv,    WpQ,  256,  768, 512);
  packW<<<dim3(1,256),blk,0,stream>>>(wproj, WpP,  256,  256,   0);
  packW<<<dim3(1,1024),blk,0,stream>>>(wfc1, WpF1, 256, 1024,   0);
  packW<<<dim3(4,256),blk,0,stream>>>(wfc2,  WpF2, 1024, 256,   0);
  packBn3<<<dim3(4),blk,0,stream>>>(bn_q, bn_k, bn_v, bnQ);

  // fused QKV GEMM -> spikes
  sgemm<C_,768,false,0,float><<<dim3(4,24,16),blk,0,stream>>>(
      x, WpQ, nullptr, bnQ, nullptr, qkv, 1.0f);
  kv_kernel<<<dim3(T_*B_*HEADS_),blk,0,stream>>>(qkv, kvb);
  attn_lif_kernel<<<dim3(4,HEADS_,B_),blk,0,stream>>>(qkv, kvb, as_);
  // proj -> xnew = x + attn spike
  sgemm<C_,C_,true,1,uint8_t><<<dim3(4,8,16),blk,0,stream>>>(
      as_, WpP, bproj, bnproj, x, xnew, 1.0f);
  // fc1 -> h1 spikes (overlays dead qkv/as_)
  sgemm<C_,HD_,true,0,float><<<dim3(4,32,16),blk,0,stream>>>(
      xnew, WpF1, bfc1, bnfc1, nullptr, h1s, 1.0f);
  // fc2 -> out = xnew + mlp spike
  sgemm<HD_,C_,true,1,uint8_t><<<dim3(4,8,16),blk,0,stream>>>(
      h1s, WpF2, bfc2, bnfc2, xnew, d_out, 1.0f);
}